// Round 1
// 315.708 us; speedup vs baseline: 1.0396x; 1.0396x over previous
//
#include <hip/hip_runtime.h>

// Shift-TCN fused pipeline v2, MI355X (gfx950).
// Algebra: shift_in(bn1(x)) = sc * shift_raw(x) + tc * w1(c,t); fold sc into W,
// fold tc-term into per-(o,t) bias = b2all[o] - [t==0]*S0[o] - [t==63]*S63[o].
// [memset acc=0]
// [K12] single x pass: BN1 partial stats (atomic) + ht_raw = bf16(shift_raw(x)) [j][c]
// [Kp ] params: sc/tc -> W'b = bf16(W*sc), b2all/S0/S63 (rank-corrections)
// [K3 ] MFMA GEMM o-tile=256 (ht read ONCE), j-tile=128, epilogue bias+relu,
//       LDS-transposed coalesced y stores (256B segments)
// [K4 ] shift_out + BN2 partial stats (atomic)
// [K5 ] shift_out + BN2 affine -> out (fp32)

#define EPSV 1e-5f
constexpr int Nn = 64, Cc = 256, Tt = 64, Vv = 25;
constexpr int TV = Tt * Vv;          // 1600
constexpr int CTV = Cc * TV;         // 409600
constexpr float Minv = 1.0f / (Nn * TV);   // 1/102400

typedef short short8 __attribute__((ext_vector_type(8)));
typedef float floatx4 __attribute__((ext_vector_type(4)));

__device__ __forceinline__ unsigned short f2bf(float f) {
    unsigned int u = __builtin_bit_cast(unsigned int, f);
    u += 0x7FFFu + ((u >> 16) & 1u);      // round-to-nearest-even
    return (unsigned short)(u >> 16);
}
__device__ __forceinline__ float bf2f(unsigned short h) {
    unsigned int u = ((unsigned int)h) << 16;
    return __builtin_bit_cast(float, u);
}
__device__ __forceinline__ void gload_lds16(const void* g, void* l) {
    __builtin_amdgcn_global_load_lds((const __attribute__((address_space(1))) void*)g,
                                     (__attribute__((address_space(3))) void*)l, 16, 0, 0);
}

// ------- K12: fused BN1 stats + shift_raw + bf16 transpose-store -------
// grid (4 cgrp(64ch), 8 ttile(200tv), 64 n), block 256.
// LDS x-tile transposed [tvwin=256][68pad] fp32; ht writes 128B segments.
__global__ __launch_bounds__(256) void k_stats_shift(const float* __restrict__ x,
                                                     const float* __restrict__ theta,
                                                     float* __restrict__ sacc,
                                                     float* __restrict__ qacc,
                                                     unsigned short* __restrict__ ht) {
    int c0 = blockIdx.x * 64;
    int E0 = blockIdx.y * 200;
    int n  = blockIdx.z;
    int tid = threadIdx.x;
    __shared__ __attribute__((aligned(16))) float xt[256][68];
    __shared__ int   pd[64];
    __shared__ float pf[64];
    if (tid < 64) {
        float th = theta[c0 + tid];
        float fd = floorf(th);
        pd[tid] = (int)fd;        // d in {-1, 0} for theta in [-1,1)
        pf[tid] = th - fd;
    }
    int lo = E0 - 28; if (lo < 0) lo = 0;
    int hi = E0 + 228; if (hi > 1600) hi = 1600;
    int ldsoff = lo - (E0 - 28);             // 0 or 28, multiple of 4
    int nf4 = (hi - lo) >> 2;
    {   // stage x[c0..c0+63][lo..hi) -> xt[row=tv-(E0-28)][c] (transposed)
        int ci = tid >> 2, li = tid & 3;
        const float4* xrow = (const float4*)(x + (size_t)n * CTV + (size_t)(c0 + ci) * TV + lo);
        for (int i = li; i < nf4; i += 4) {
            float4 v = xrow[i];
            int r = ldsoff + i * 4;
            xt[r][ci] = v.x; xt[r + 1][ci] = v.y; xt[r + 2][ci] = v.z; xt[r + 3][ci] = v.w;
        }
    }
    __syncthreads();
    {   // BN1 partial stats over core rows [28,228) == tv [E0, E0+200)
        int ci = tid >> 2, li = tid & 3;
        float s = 0.f, q = 0.f;
        for (int r = 28 + li; r < 228; r += 4) {
            float v = xt[r][ci];
            s += v; q += v * v;
        }
        s += __shfl_down(s, 2); q += __shfl_down(q, 2);
        s += __shfl_down(s, 1); q += __shfl_down(q, 1);
        if (li == 0) { atomicAdd(&sacc[c0 + ci], s); atomicAdd(&qacc[c0 + ci], q); }
    }
    // shift_raw + bf16 pack, store [j][c] with 128B-contiguous segments
    int cseg = tid & 7, er = tid >> 3;
    int cb = cseg * 8;
    for (int it = 0; it < 7; ++it) {
        int tv_l = er + it * 32;
        if (tv_l >= 200) break;
        int e = E0 + tv_l;
        int t = e / 25;
        const float* rA = &xt[tv_l + 3][cb];    // tv + d*25, d=-1
        const float* rB = &xt[tv_l + 28][cb];   // tv (d=0 x0; d=-1 x1)
        const float* rC = &xt[tv_l + 53][cb];   // tv + 25 (d=0 x1)
        float4 a0 = *(const float4*)rA, a1 = *(const float4*)(rA + 4);
        float4 b0 = *(const float4*)rB, b1 = *(const float4*)(rB + 4);
        float4 g0 = *(const float4*)rC, g1 = *(const float4*)(rC + 4);
        float A8[8] = {a0.x, a0.y, a0.z, a0.w, a1.x, a1.y, a1.z, a1.w};
        float B8[8] = {b0.x, b0.y, b0.z, b0.w, b1.x, b1.y, b1.z, b1.w};
        float C8[8] = {g0.x, g0.y, g0.z, g0.w, g1.x, g1.y, g1.z, g1.w};
        unsigned int w4[4];
#pragma unroll
        for (int k = 0; k < 8; ++k) {
            int c = cb + k;
            int d = pd[c]; float f = pf[c];
            int i0 = t + d;
            float x0 = (d < 0) ? A8[k] : B8[k];
            float x1 = (d < 0) ? B8[k] : C8[k];
            float v0 = ((unsigned)i0 < 64u) ? x0 : 0.f;
            float v1 = ((unsigned)(i0 + 1) < 64u) ? x1 : 0.f;
            unsigned short hb = f2bf(v0 + f * (v1 - v0));
            if (k & 1) w4[k >> 1] |= ((unsigned int)hb) << 16;
            else       w4[k >> 1] = hb;
        }
        uint4 st = { w4[0], w4[1], w4[2], w4[3] };
        *(uint4*)(ht + (size_t)(n * 1600 + e) * 256 + c0 + cb) = st;
    }
}

// ------- Kp: finalize BN1 params; W'b = bf16(W*sc); rank-corrections -------
// grid (256 o), block 256 (c).
__global__ __launch_bounds__(256) void k_params(const float* __restrict__ w,
                                                const float* __restrict__ bias,
                                                const float* __restrict__ sacc,
                                                const float* __restrict__ qacc,
                                                const float* __restrict__ g,
                                                const float* __restrict__ b,
                                                const float* __restrict__ theta,
                                                unsigned short* __restrict__ wb,
                                                float* __restrict__ b2all,
                                                float* __restrict__ s0v,
                                                float* __restrict__ s63v) {
    int o = blockIdx.x, c = threadIdx.x;
    float mean = sacc[c] * Minv;
    float var  = qacc[c] * Minv - mean * mean;
    float sc = g[c] * rsqrtf(var + EPSV);
    float tc = b[c] - mean * sc;
    float th = theta[c];
    float fd = floorf(th);
    int d = (int)fd;
    float f = th - fd;
    float wv = w[o * 256 + c];
    wb[o * 256 + c] = f2bf(wv * sc);
    float wtc = wv * tc;
    float r0  = (d < 0) ? wtc * (1.f - f) : 0.f;   // t==0 correction (d==-1)
    float r63 = (d == 0) ? wtc * f : 0.f;          // t==63 correction (d==0)
    for (int off = 32; off; off >>= 1) {
        wtc += __shfl_down(wtc, off);
        r0  += __shfl_down(r0, off);
        r63 += __shfl_down(r63, off);
    }
    __shared__ float aux[3][4];
    if ((c & 63) == 0) { int wv_i = c >> 6; aux[0][wv_i] = wtc; aux[1][wv_i] = r0; aux[2][wv_i] = r63; }
    __syncthreads();
    if (c == 0) {
        float sw  = aux[0][0] + aux[0][1] + aux[0][2] + aux[0][3];
        float s0  = aux[1][0] + aux[1][1] + aux[1][2] + aux[1][3];
        float s63 = aux[2][0] + aux[2][1] + aux[2][2] + aux[2][3];
        b2all[o] = bias[o] + sw;
        s0v[o] = s0;
        s63v[o] = s63;
    }
}

// ------- K3: y = relu(W' ht + bias2). o-tile=256 (ht read once), j-tile=128 -------
// grid (800), block 256 (4 waves). LDS: stage A 16KB + B 8KB, union'd with
// C-transpose tile [256][136] bf16 for coalesced uint4 y stores.
__global__ __launch_bounds__(256, 2) void k_gemm(const unsigned short* __restrict__ ht,
                                                 const unsigned short* __restrict__ wb,
                                                 const float* __restrict__ b2all,
                                                 const float* __restrict__ s0v,
                                                 const float* __restrict__ s63v,
                                                 unsigned short* __restrict__ y) {
    int j0 = blockIdx.x * 128;
    int tid = threadIdx.x;
    int w = tid >> 6, lane = tid & 63;
    int quad = lane >> 4, l16 = lane & 15;
    __shared__ __attribute__((aligned(16))) unsigned short smem[256 * 136]; // 69,632 B
    unsigned short* A = smem;              // [256 o][32 k]
    unsigned short* B = smem + 256 * 32;   // [128 j][32 k]
    floatx4 acc[4][8] = {};
    int srowA = w * 64 + (lane >> 2);
    int srowB = w * 32 + (lane >> 2);
    int skc = (lane & 3) * 8;              // shorts
    const unsigned short* wp = wb + (size_t)srowA * 256 + skc;
    const unsigned short* hp = ht + (size_t)(j0 + srowB) * 256 + skc;
    for (int k0 = 0; k0 < 256; k0 += 32) {
        __syncthreads();                   // prev iter's frag reads done
#pragma unroll
        for (int a = 0; a < 4; ++a)
            gload_lds16(wp + (size_t)a * 16 * 256 + k0, A + (w * 64 + a * 16) * 32);
#pragma unroll
        for (int a = 0; a < 2; ++a)
            gload_lds16(hp + (size_t)a * 16 * 256 + k0, B + (w * 32 + a * 16) * 32);
        __syncthreads();                   // vmcnt drained at barrier
        short8 af[4], bf[8];
#pragma unroll
        for (int m = 0; m < 4; ++m)
            af[m] = *(const short8*)&A[(w * 64 + m * 16 + l16) * 32 + quad * 8];
#pragma unroll
        for (int jt = 0; jt < 8; ++jt)
            bf[jt] = *(const short8*)&B[(jt * 16 + l16) * 32 + quad * 8];
#pragma unroll
        for (int m = 0; m < 4; ++m)
#pragma unroll
            for (int jt = 0; jt < 8; ++jt)
                acc[m][jt] = __builtin_amdgcn_mfma_f32_16x16x32_bf16(af[m], bf[jt], acc[m][jt], 0, 0, 0);
    }
    __syncthreads();                       // before overwriting smem as C-tile
    unsigned short* Cl = smem;             // [256 o][136 pad] bf16
#pragma unroll
    for (int m = 0; m < 4; ++m) {
        int ob = w * 64 + m * 16 + quad * 4;
#pragma unroll
        for (int r = 0; r < 4; ++r) {
            int o = ob + r;
            float bb = b2all[o], e0 = s0v[o], e63 = s63v[o];
#pragma unroll
            for (int jt = 0; jt < 8; ++jt) {
                int jj = j0 + jt * 16;
                int nn = jj / 1600;
                int tvb = jj - nn * 1600 + l16;
                float bia = bb - (tvb < 25 ? e0 : 0.f) - (tvb >= 1575 ? e63 : 0.f);
                float v = acc[m][jt][r] + bia;
                v = v > 0.f ? v : 0.f;
                Cl[o * 136 + jt * 16 + l16] = f2bf(v);
            }
        }
    }
    __syncthreads();
    int li = tid & 15, orow = tid >> 4;
#pragma unroll
    for (int pass = 0; pass < 16; ++pass) {
        int o = orow + pass * 16;
        uint4 vv = *(const uint4*)&Cl[o * 136 + li * 8];
        int j = j0 + li * 8;
        int nn = j / 1600;
        int tv = j - nn * 1600;
        *(uint4*)(y + (size_t)nn * CTV + (size_t)o * TV + tv) = vv;
    }
}

// ------- K4: BN2 partial stats over z = shift_out(y). grid (8 ngrp, 256 o) -------
__global__ __launch_bounds__(256) void k_bn2_stats(const unsigned short* __restrict__ y,
                                                   const float* __restrict__ theta,
                                                   float* __restrict__ sacc,
                                                   float* __restrict__ qacc) {
    int o = blockIdx.y, ng = blockIdx.x, tid = threadIdx.x;
    __shared__ __attribute__((aligned(16))) unsigned short row[1600];
    float th = theta[o];
    float fd = floorf(th);
    int d = (int)fd;
    float f = th - fd;
    float s = 0.f, q = 0.f;
    for (int n = ng * 8; n < ng * 8 + 8; ++n) {
        const uint4* yp = (const uint4*)(y + (size_t)n * CTV + (size_t)o * TV);
        __syncthreads();
        if (tid < 200) ((uint4*)row)[tid] = yp[tid];
        __syncthreads();
        for (int e = tid; e < 1600; e += 256) {
            int t = e / 25, v = e - t * 25;
            int i0 = t + d, i1 = i0 + 1;
            float a0 = ((unsigned)i0 < 64u) ? bf2f(row[i0 * 25 + v]) : 0.f;
            float a1 = ((unsigned)i1 < 64u) ? bf2f(row[i1 * 25 + v]) : 0.f;
            float z = (1.f - f) * a0 + f * a1;
            s += z; q += z * z;
        }
    }
    for (int off = 32; off; off >>= 1) { s += __shfl_down(s, off); q += __shfl_down(q, off); }
    if ((tid & 63) == 0) { atomicAdd(&sacc[o], s); atomicAdd(&qacc[o], q); }
}

// ------- K5: out = BN2(shift_out(y)) fp32. grid (64 n, 256 o) -------
__global__ __launch_bounds__(256) void k_bn2_apply(const unsigned short* __restrict__ y,
                                                   const float* __restrict__ theta,
                                                   const float* __restrict__ sacc,
                                                   const float* __restrict__ qacc,
                                                   const float* __restrict__ g,
                                                   const float* __restrict__ b,
                                                   float* __restrict__ out) {
    int o = blockIdx.y, n = blockIdx.x, tid = threadIdx.x;
    __shared__ __attribute__((aligned(16))) unsigned short row[1600];
    float th = theta[o];
    float fd = floorf(th);
    int d = (int)fd;
    float f = th - fd;
    float mean = sacc[o] * Minv;
    float var = qacc[o] * Minv - mean * mean;
    float sc = g[o] * rsqrtf(var + EPSV);
    float tc = b[o] - mean * sc;
    const uint4* yp = (const uint4*)(y + (size_t)n * CTV + (size_t)o * TV);
    if (tid < 200) ((uint4*)row)[tid] = yp[tid];
    __syncthreads();
    float4* op = (float4*)(out + (size_t)n * CTV + (size_t)o * TV);
    for (int i = tid; i < 400; i += 256) {
        float4 r;
        int e = i * 4;
#pragma unroll
        for (int k = 0; k < 4; ++k) {
            int ee = e + k;
            int t = ee / 25, v = ee - t * 25;
            int i0 = t + d, i1 = i0 + 1;
            float a0 = ((unsigned)i0 < 64u) ? bf2f(row[i0 * 25 + v]) : 0.f;
            float a1 = ((unsigned)i1 < 64u) ? bf2f(row[i1 * 25 + v]) : 0.f;
            ((float*)&r)[k] = ((1.f - f) * a0 + f * a1) * sc + tc;
        }
        op[i] = r;
    }
}

extern "C" void kernel_launch(void* const* d_in, const int* in_sizes, int n_in,
                              void* d_out, int out_size, void* d_ws, size_t ws_size,
                              hipStream_t stream) {
    const float* x      = (const float*)d_in[0];
    const float* conv_w = (const float*)d_in[1];
    const float* conv_b = (const float*)d_in[2];
    const float* bn1_g  = (const float*)d_in[3];
    const float* bn1_b  = (const float*)d_in[4];
    const float* bn2_g  = (const float*)d_in[5];
    const float* bn2_b  = (const float*)d_in[6];
    const float* th_in  = (const float*)d_in[7];
    const float* th_out = (const float*)d_in[8];
    float* out = (float*)d_out;

    char* ws = (char*)d_ws;
    unsigned short* ht = (unsigned short*)ws;                   // 52,428,800 B
    unsigned short* yy = (unsigned short*)(ws + 52428800);      // 52,428,800 B
    unsigned short* wb = (unsigned short*)(ws + 104857600);     // 131,072 B
    float* sacc1 = (float*)(ws + 104988672);
    float* qacc1 = sacc1 + 256;
    float* sacc2 = qacc1 + 256;
    float* qacc2 = sacc2 + 256;
    float* b2all = qacc2 + 256;
    float* s0v   = b2all + 256;
    float* s63v  = s0v + 256;

    hipMemsetAsync((void*)sacc1, 0, 4 * 256 * sizeof(float), stream);
    hipLaunchKernelGGL(k_stats_shift, dim3(4, 8, 64), dim3(256), 0, stream,
                       x, th_in, sacc1, qacc1, ht);
    hipLaunchKernelGGL(k_params, dim3(256), dim3(256), 0, stream,
                       conv_w, conv_b, sacc1, qacc1, bn1_g, bn1_b, th_in,
                       wb, b2all, s0v, s63v);
    hipLaunchKernelGGL(k_gemm, dim3(800), dim3(256), 0, stream,
                       ht, wb, b2all, s0v, s63v, yy);
    hipLaunchKernelGGL(k_bn2_stats, dim3(8, 256), dim3(256), 0, stream, yy, th_out, sacc2, qacc2);
    hipLaunchKernelGGL(k_bn2_apply, dim3(64, 256), dim3(256), 0, stream,
                       yy, th_out, sacc2, qacc2, bn2_g, bn2_b, out);
}